// Round 8
// baseline (381.136 us; speedup 1.0000x reference)
//
#include <hip/hip_runtime.h>

// LoRALinear: out = x @ (W + 2 * B@A)^T + b
// Fold LoRA into W' (bf16), convert x to bf16, one 256x256-tile MFMA GEMM.
// r8: reads spread 8/8/4/4 across phases so per-phase LDS read time < MFMA
// window (LDS-BW hiding); stage cadence A(t+1) early / B(t+2) late.

static constexpr int Mdim = 8192;
static constexpr int Ndim = 4096;
static constexpr int Kdim = 4096;
#define LORA_SCALE 2.0f   // alpha/rank = 32/16

typedef __bf16 bf16;
typedef __bf16 bf16x8 __attribute__((ext_vector_type(8)));
typedef __bf16 bf16x4 __attribute__((ext_vector_type(4)));
typedef float f32x4 __attribute__((ext_vector_type(4)));

__device__ __forceinline__ void gload_lds16(const void* g, void* l) {
  __builtin_amdgcn_global_load_lds(
      (const __attribute__((address_space(1))) unsigned int*)g,
      (__attribute__((address_space(3))) unsigned int*)l, 16, 0, 0);
}

// ---------------- kernel 1: x fp32 -> bf16 ----------------
__global__ __launch_bounds__(256) void cvt_x_kernel(const float* __restrict__ x,
                                                    bf16* __restrict__ xb, int n8) {
  for (int i = blockIdx.x * blockDim.x + threadIdx.x; i < n8;
       i += gridDim.x * blockDim.x) {
    const float4* p = reinterpret_cast<const float4*>(x) + (size_t)i * 2;
    float4 a = p[0];
    float4 c = p[1];
    bf16x8 o;
    o[0] = (bf16)a.x; o[1] = (bf16)a.y; o[2] = (bf16)a.z; o[3] = (bf16)a.w;
    o[4] = (bf16)c.x; o[5] = (bf16)c.y; o[6] = (bf16)c.z; o[7] = (bf16)c.w;
    reinterpret_cast<bf16x8*>(xb)[i] = o;
  }
}

// ---------------- kernel 2: W' = W + 2*B@A  (bf16) ----------------
__global__ __launch_bounds__(256) void build_w_kernel(const float* __restrict__ W,
                                                      const float* __restrict__ lA,
                                                      const float* __restrict__ lB,
                                                      bf16* __restrict__ wb) {
  const int n0 = blockIdx.x * 8;
  const int t = threadIdx.x;
  __shared__ float bs[8][16];
  if (t < 128) bs[t >> 4][t & 15] = lB[(n0 + (t >> 4)) * 16 + (t & 15)] * LORA_SCALE;
  __syncthreads();
  for (int k0 = t * 4; k0 < Kdim; k0 += 1024) {
    float4 acc[8];
#pragma unroll
    for (int j = 0; j < 8; ++j)
      acc[j] = *reinterpret_cast<const float4*>(&W[(size_t)(n0 + j) * Kdim + k0]);
#pragma unroll
    for (int r = 0; r < 16; ++r) {
      float4 a = *reinterpret_cast<const float4*>(&lA[r * Kdim + k0]);
#pragma unroll
      for (int j = 0; j < 8; ++j) {
        acc[j].x += bs[j][r] * a.x;
        acc[j].y += bs[j][r] * a.y;
        acc[j].z += bs[j][r] * a.z;
        acc[j].w += bs[j][r] * a.w;
      }
    }
#pragma unroll
    for (int j = 0; j < 8; ++j) {
      bf16x4 o;
      o[0] = (bf16)acc[j].x; o[1] = (bf16)acc[j].y;
      o[2] = (bf16)acc[j].z; o[3] = (bf16)acc[j].w;
      *reinterpret_cast<bf16x4*>(&wb[(size_t)(n0 + j) * Kdim + k0]) = o;
    }
  }
}

// ---------------- kernel 3: 256x256 read-spread bf16 MFMA GEMM ----------------
// 8 waves (2M x 4N), per-wave 128x64. BK=64, 64 K-tiles, dbuf by K-tile.
// LDS half = 16KB [kc8][row 0..127][8bf16]; A halves rows 0-127/128-255, B same by col.
// Phases (16 MFMA each), reads spread so LDS-read/phase < MFMA window:
//   ph0: read b(ks0)x4 + a(ks0)lo x4 (8); stage A(t+1)h0 (other buf); lgkm0; MFMA ks0·lo
//   ph1: read b(ks1)x4 + a(ks0)hi x4 (8); stage A(t+1)h1;             lgkm0; MFMA ks0·hi
//   MID BARRIER  (all B-reads of tile t retired -> B(t+2) may overwrite cur buf)
//   ph2: read a(ks1)lo x4 (4); stage B(t+2)h0 (cur buf); lgkm0; MFMA ks1·lo
//   ph3: read a(ks1)hi x4 (4); stage B(t+2)h1;           lgkm0; MFMA ks1·hi
// Tile top: vmcnt(4) (leaves B(t+1)'s 4 loads) + BAR; vmcnt(0) at t=63.
// Prologue: A0,B0,B1 (12 loads); tile t stages A(t+1) [t<63], B(t+2) [t<62].
#define LGKM0_FENCE                                              \
  asm volatile("s_waitcnt lgkmcnt(0)" ::: "memory");             \
  __builtin_amdgcn_sched_barrier(0);

__global__ __launch_bounds__(512, 2) void gemm8(const bf16* __restrict__ Xb,
                                                const bf16* __restrict__ Wb,
                                                const float* __restrict__ bias,
                                                float* __restrict__ out) {
  extern __shared__ char smem[];  // 131072 bytes
  const int tid = threadIdx.x;
  const int lane = tid & 63;
  const int wid = tid >> 6;
  const int wm = wid >> 2, wn = wid & 3;  // 2 x 4 wave grid
  const int r16 = lane & 15;
  const int kq = lane >> 4;  // 0..3

  // XCD-aware bijective swizzle (512 wgs, 512 % 8 == 0)
  const int wg = blockIdx.x;
  const int swz = (wg & 7) * 64 + (wg >> 3);
  const int bm0 = (swz & 31) * 256;  // 32 M-tiles
  const int bn0 = (swz >> 5) * 256;  // 16 N-tiles

  // fragment byte offsets within a 64KB buffer (+ks*8192 +mi/nj*256 later)
  const int aBase = wm * 16384 + kq * 2048 + r16 * 16;
  const int bBase = 32768 + (wn >> 1) * 16384 + kq * 2048 + ((wn & 1) * 64 + r16) * 16;

  // staging: thread t covers (row=t&127, kc8=t>>7) and (row, kc8+4) of a half
  const bf16* aRow = Xb + (size_t)(bm0 + (tid & 127)) * Kdim + (tid >> 7) * 8;
  const bf16* bRow = Wb + (size_t)(bn0 + (tid & 127)) * Kdim + (tid >> 7) * 8;

  auto stageA = [&](int kt, int h, char* buf) {
    const bf16* s = aRow + (size_t)h * 128 * Kdim + kt * 64;
    char* d = buf + h * 16384 + tid * 16;
    gload_lds16(s, d);
    gload_lds16(s + 32, d + 8192);
  };
  auto stageB = [&](int kt, int h, char* buf) {
    const bf16* s = bRow + (size_t)h * 128 * Kdim + kt * 64;
    char* d = buf + 32768 + h * 16384 + tid * 16;
    gload_lds16(s, d);
    gload_lds16(s + 32, d + 8192);
  };
#define ABUF(d) (smem + (d) * 65536)

  f32x4 acc[8][4] = {};
  bf16x8 a0[8], a1[8], b0[4], b1[4];

  // prologue: A(0), B(0) into buf0; B(1) into buf1  (12 loads)
  stageA(0, 0, ABUF(0));
  stageA(0, 1, ABUF(0));
  stageB(0, 0, ABUF(0));
  stageB(0, 1, ABUF(0));
  stageB(1, 0, ABUF(1));
  stageB(1, 1, ABUF(1));

  for (int t = 0; t < 64; ++t) {
    if (t == 63) {
      asm volatile("s_waitcnt vmcnt(0)" ::: "memory");
    } else {
      asm volatile("s_waitcnt vmcnt(4)" ::: "memory");
    }
    __builtin_amdgcn_s_barrier();
    char* Ab = ABUF(t & 1);

    // ---- ph0: b(ks0) + a(ks0) lo; stage A(t+1)h0 (other buffer)
#pragma unroll
    for (int nj = 0; nj < 4; ++nj)
      b0[nj] = *reinterpret_cast<const bf16x8*>(Ab + bBase + nj * 256);
#pragma unroll
    for (int mi = 0; mi < 4; ++mi)
      a0[mi] = *reinterpret_cast<const bf16x8*>(Ab + aBase + mi * 256);
    if (t < 63) stageA(t + 1, 0, ABUF((t + 1) & 1));
    LGKM0_FENCE
    __builtin_amdgcn_s_setprio(1);
#pragma unroll
    for (int mi = 0; mi < 4; ++mi)
#pragma unroll
      for (int nj = 0; nj < 4; ++nj)
        acc[mi][nj] = __builtin_amdgcn_mfma_f32_16x16x32_bf16(a0[mi], b0[nj],
                                                              acc[mi][nj], 0, 0, 0);
    __builtin_amdgcn_s_setprio(0);

    // ---- ph1: b(ks1) + a(ks0) hi; stage A(t+1)h1
#pragma unroll
    for (int nj = 0; nj < 4; ++nj)
      b1[nj] = *reinterpret_cast<const bf16x8*>(Ab + 8192 + bBase + nj * 256);
#pragma unroll
    for (int mi = 4; mi < 8; ++mi)
      a0[mi] = *reinterpret_cast<const bf16x8*>(Ab + aBase + mi * 256);
    if (t < 63) stageA(t + 1, 1, ABUF((t + 1) & 1));
    LGKM0_FENCE
    __builtin_amdgcn_s_setprio(1);
#pragma unroll
    for (int mi = 4; mi < 8; ++mi)
#pragma unroll
      for (int nj = 0; nj < 4; ++nj)
        acc[mi][nj] = __builtin_amdgcn_mfma_f32_16x16x32_bf16(a0[mi], b0[nj],
                                                              acc[mi][nj], 0, 0, 0);
    __builtin_amdgcn_s_setprio(0);
    __builtin_amdgcn_sched_barrier(0);
    __builtin_amdgcn_s_barrier();  // mid: all B-reads of tile t retired block-wide

    // ---- ph2: a(ks1) lo; stage B(t+2)h0 (current buffer, B-region now free)
#pragma unroll
    for (int mi = 0; mi < 4; ++mi)
      a1[mi] = *reinterpret_cast<const bf16x8*>(Ab + 8192 + aBase + mi * 256);
    if (t < 62) stageB(t + 2, 0, Ab);
    LGKM0_FENCE
    __builtin_amdgcn_s_setprio(1);
#pragma unroll
    for (int mi = 0; mi < 4; ++mi)
#pragma unroll
      for (int nj = 0; nj < 4; ++nj)
        acc[mi][nj] = __builtin_amdgcn_mfma_f32_16x16x32_bf16(a1[mi], b1[nj],
                                                              acc[mi][nj], 0, 0, 0);
    __builtin_amdgcn_s_setprio(0);

    // ---- ph3: a(ks1) hi; stage B(t+2)h1
#pragma unroll
    for (int mi = 4; mi < 8; ++mi)
      a1[mi] = *reinterpret_cast<const bf16x8*>(Ab + 8192 + aBase + mi * 256);
    if (t < 62) stageB(t + 2, 1, Ab);
    LGKM0_FENCE
    __builtin_amdgcn_s_setprio(1);
#pragma unroll
    for (int mi = 4; mi < 8; ++mi)
#pragma unroll
      for (int nj = 0; nj < 4; ++nj)
        acc[mi][nj] = __builtin_amdgcn_mfma_f32_16x16x32_bf16(a1[mi], b1[nj],
                                                              acc[mi][nj], 0, 0, 0);
    __builtin_amdgcn_s_setprio(0);
    __builtin_amdgcn_sched_barrier(0);
  }

  // epilogue: C/D map col=lane&15, row=(lane>>4)*4+reg
  const int crow0 = bm0 + wm * 128 + (lane >> 4) * 4;
  const int ccol0 = bn0 + wn * 64 + r16;
#pragma unroll
  for (int nj = 0; nj < 4; ++nj) {
    float bv = bias[ccol0 + nj * 16];
#pragma unroll
    for (int mi = 0; mi < 8; ++mi)
#pragma unroll
      for (int r = 0; r < 4; ++r)
        out[(size_t)(crow0 + mi * 16 + r) * Ndim + ccol0 + nj * 16] =
            acc[mi][nj][r] + bv;
  }
#undef ABUF
}

// ---------------- fallback (ws too small): fp32 tiled GEMM, fold on stage ----------------
__global__ __launch_bounds__(256) void gemm_fallback(const float* __restrict__ x,
                                                     const float* __restrict__ W,
                                                     const float* __restrict__ bias,
                                                     const float* __restrict__ lA,
                                                     const float* __restrict__ lB,
                                                     float* __restrict__ out) {
  __shared__ float xs[16][64];
  __shared__ float wt[16][64];
  const int t = threadIdx.x;
  const int tx = t & 15, ty = t >> 4;
  const int bm0 = blockIdx.y * 64, bn0 = blockIdx.x * 64;
  float acc[4][4] = {};
  for (int kt = 0; kt < Kdim; kt += 16) {
    __syncthreads();
    for (int e = t; e < 1024; e += 256) {
      int m = e >> 4, k = e & 15;
      xs[k][m] = x[(size_t)(bm0 + m) * Kdim + kt + k];
    }
    for (int e = t; e < 1024; e += 256) {
      int n = e >> 4, k = e & 15;
      float v = W[(size_t)(bn0 + n) * Kdim + kt + k];
#pragma unroll
      for (int r = 0; r < 16; ++r)
        v += LORA_SCALE * lB[(bn0 + n) * 16 + r] * lA[r * Kdim + kt + k];
      wt[k][n] = v;
    }
    __syncthreads();
#pragma unroll
    for (int k = 0; k < 16; ++k) {
      float xa[4], wv[4];
#pragma unroll
      for (int i = 0; i < 4; ++i) xa[i] = xs[k][ty * 4 + i];
#pragma unroll
      for (int j = 0; j < 4; ++j) wv[j] = wt[k][tx * 4 + j];
#pragma unroll
      for (int i = 0; i < 4; ++i)
#pragma unroll
        for (int j = 0; j < 4; ++j) acc[i][j] += xa[i] * wv[j];
    }
  }
#pragma unroll
  for (int i = 0; i < 4; ++i)
#pragma unroll
    for (int j = 0; j < 4; ++j)
      out[(size_t)(bm0 + ty * 4 + i) * Ndim + bn0 + tx * 4 + j] =
          acc[i][j] + bias[bn0 + tx * 4 + j];
}

extern "C" void kernel_launch(void* const* d_in, const int* in_sizes, int n_in,
                              void* d_out, int out_size, void* d_ws, size_t ws_size,
                              hipStream_t stream) {
  const float* x = (const float*)d_in[0];
  const float* W = (const float*)d_in[1];
  const float* b = (const float*)d_in[2];
  const float* lA = (const float*)d_in[3];
  const float* lB = (const float*)d_in[4];
  float* out = (float*)d_out;

  const size_t xb_bytes = (size_t)Mdim * Kdim * sizeof(bf16);
  const size_t wb_bytes = (size_t)Ndim * Kdim * sizeof(bf16);

  if (ws_size >= xb_bytes + wb_bytes) {
    bf16* xb = (bf16*)d_ws;
    bf16* wb = (bf16*)((char*)d_ws + xb_bytes);
    cvt_x_kernel<<<4096, 256, 0, stream>>>(x, xb, Mdim * Kdim / 8);
    build_w_kernel<<<Ndim / 8, 256, 0, stream>>>(W, lA, lB, wb);
    (void)hipFuncSetAttribute((const void*)gemm8,
                              hipFuncAttributeMaxDynamicSharedMemorySize, 131072);
    gemm8<<<dim3((Mdim / 256) * (Ndim / 256)), dim3(512), 131072, stream>>>(xb, wb, b,
                                                                            out);
  } else {
    dim3 grid(Ndim / 64, Mdim / 64);
    gemm_fallback<<<grid, 64 * 4, 0, stream>>>(x, W, b, lA, lB, out);
  }
}

// Round 9
// 325.698 us; speedup vs baseline: 1.1702x; 1.1702x over previous
//
#include <hip/hip_runtime.h>

// LoRALinear: out = x @ (W + 2 * B@A)^T + b
// Fold LoRA into W' (bf16), convert x to bf16, one 256x256-tile MFMA GEMM.
// r9: LDS layout swapped to row-major [row][64] (128B stride) with
// byte ^= ((row&7)<<4) XOR swizzle (m214-verified full-rate pattern);
// schedule identical to r8 (read-spread 8/8/4/4, counted vmcnt, 2 bars/tile).

static constexpr int Mdim = 8192;
static constexpr int Ndim = 4096;
static constexpr int Kdim = 4096;
#define LORA_SCALE 2.0f   // alpha/rank = 32/16

typedef __bf16 bf16;
typedef __bf16 bf16x8 __attribute__((ext_vector_type(8)));
typedef __bf16 bf16x4 __attribute__((ext_vector_type(4)));
typedef float f32x4 __attribute__((ext_vector_type(4)));

__device__ __forceinline__ void gload_lds16(const void* g, void* l) {
  __builtin_amdgcn_global_load_lds(
      (const __attribute__((address_space(1))) unsigned int*)g,
      (__attribute__((address_space(3))) unsigned int*)l, 16, 0, 0);
}

// ---------------- kernel 1: x fp32 -> bf16 ----------------
__global__ __launch_bounds__(256) void cvt_x_kernel(const float* __restrict__ x,
                                                    bf16* __restrict__ xb, int n8) {
  for (int i = blockIdx.x * blockDim.x + threadIdx.x; i < n8;
       i += gridDim.x * blockDim.x) {
    const float4* p = reinterpret_cast<const float4*>(x) + (size_t)i * 2;
    float4 a = p[0];
    float4 c = p[1];
    bf16x8 o;
    o[0] = (bf16)a.x; o[1] = (bf16)a.y; o[2] = (bf16)a.z; o[3] = (bf16)a.w;
    o[4] = (bf16)c.x; o[5] = (bf16)c.y; o[6] = (bf16)c.z; o[7] = (bf16)c.w;
    reinterpret_cast<bf16x8*>(xb)[i] = o;
  }
}

// ---------------- kernel 2: W' = W + 2*B@A  (bf16) ----------------
__global__ __launch_bounds__(256) void build_w_kernel(const float* __restrict__ W,
                                                      const float* __restrict__ lA,
                                                      const float* __restrict__ lB,
                                                      bf16* __restrict__ wb) {
  const int n0 = blockIdx.x * 8;
  const int t = threadIdx.x;
  __shared__ float bs[8][16];
  if (t < 128) bs[t >> 4][t & 15] = lB[(n0 + (t >> 4)) * 16 + (t & 15)] * LORA_SCALE;
  __syncthreads();
  for (int k0 = t * 4; k0 < Kdim; k0 += 1024) {
    float4 acc[8];
#pragma unroll
    for (int j = 0; j < 8; ++j)
      acc[j] = *reinterpret_cast<const float4*>(&W[(size_t)(n0 + j) * Kdim + k0]);
#pragma unroll
    for (int r = 0; r < 16; ++r) {
      float4 a = *reinterpret_cast<const float4*>(&lA[r * Kdim + k0]);
#pragma unroll
      for (int j = 0; j < 8; ++j) {
        acc[j].x += bs[j][r] * a.x;
        acc[j].y += bs[j][r] * a.y;
        acc[j].z += bs[j][r] * a.z;
        acc[j].w += bs[j][r] * a.w;
      }
    }
#pragma unroll
    for (int j = 0; j < 8; ++j) {
      bf16x4 o;
      o[0] = (bf16)acc[j].x; o[1] = (bf16)acc[j].y;
      o[2] = (bf16)acc[j].z; o[3] = (bf16)acc[j].w;
      *reinterpret_cast<bf16x4*>(&wb[(size_t)(n0 + j) * Kdim + k0]) = o;
    }
  }
}

// ---------------- kernel 3: 256x256 bf16 MFMA GEMM, swizzled row-major LDS ----------------
// 8 waves (2M x 4N), per-wave 128x64. BK=64, 64 K-tiles, dbuf by K-tile (128KB).
// LDS half = 16KB row-major: logical (r in [0,128), k in [0,64)) at byte
//   r*128 + ((kchunk*16) ^ ((r&7)<<4)) + (k&7)*2      (kchunk = k>>3)
// Staging (linear gload_lds dest + inverse-swizzled per-lane SOURCE):
//   lane slot = tid*16 -> row r0 = tid>>3, chunk c0 = (tid&7)^(r0&7);
//   issue0 covers rows 0-63, issue1 rows 64-127 (same c0).
// Fragment reads: two per-lane bases (ks0/ks1; bit-6 doesn't commute with XOR).
// Schedule = r8: ph0{b0,a0lo;stageA(t+1)h0} ph1{b1,a0hi;stageA(t+1)h1} MIDBAR
//            ph2{a1lo;stageB(t+2)h0} ph3{a1hi;stageB(t+2)h1}; vmcnt(4) top gate.
#define LGKM0_FENCE                                              \
  asm volatile("s_waitcnt lgkmcnt(0)" ::: "memory");             \
  __builtin_amdgcn_sched_barrier(0);

__global__ __launch_bounds__(512, 2) void gemm8(const bf16* __restrict__ Xb,
                                                const bf16* __restrict__ Wb,
                                                const float* __restrict__ bias,
                                                float* __restrict__ out) {
  extern __shared__ char smem[];  // 131072 bytes
  const int tid = threadIdx.x;
  const int lane = tid & 63;
  const int wid = tid >> 6;
  const int wm = wid >> 2, wn = wid & 3;  // 2 x 4 wave grid
  const int r16 = lane & 15;
  const int kq = lane >> 4;  // 0..3

  // XCD-aware bijective swizzle (512 wgs, 512 % 8 == 0)
  const int wg = blockIdx.x;
  const int swz = (wg & 7) * 64 + (wg >> 3);
  const int bm0 = (swz & 31) * 256;  // 32 M-tiles
  const int bn0 = (swz >> 5) * 256;  // 16 N-tiles

  // fragment byte bases within a 64KB buffer (+mi/nj*2048 later)
  const int sx = (r16 & 7) << 4;
  const int aBase0 = wm * 16384 + r16 * 128 + ((kq * 16) ^ sx);
  const int aBase1 = wm * 16384 + r16 * 128 + ((64 + kq * 16) ^ sx);
  const int bRegion = 32768 + (wn >> 1) * 16384 + ((wn & 1) * 64 + r16) * 128;
  const int bBase0 = bRegion + ((kq * 16) ^ sx);
  const int bBase1 = bRegion + ((64 + kq * 16) ^ sx);

  // staging source: row r0 = tid>>3 within half, k-chunk c0 = (tid&7)^(r0&7)
  const int r0 = tid >> 3;
  const int c0 = (tid & 7) ^ (r0 & 7);
  const bf16* aSrc = Xb + (size_t)(bm0 + r0) * Kdim + c0 * 8;
  const bf16* bSrc = Wb + (size_t)(bn0 + r0) * Kdim + c0 * 8;
  const size_t rowJump = (size_t)64 * Kdim;  // issue1: +64 rows

  auto stageA = [&](int kt, int h, char* buf) {
    const bf16* s = aSrc + (size_t)h * 128 * Kdim + kt * 64;
    char* d = buf + h * 16384 + tid * 16;
    gload_lds16(s, d);
    gload_lds16(s + rowJump, d + 8192);
  };
  auto stageB = [&](int kt, int h, char* buf) {
    const bf16* s = bSrc + (size_t)h * 128 * Kdim + kt * 64;
    char* d = buf + 32768 + h * 16384 + tid * 16;
    gload_lds16(s, d);
    gload_lds16(s + rowJump, d + 8192);
  };
#define ABUF(d) (smem + (d) * 65536)

  f32x4 acc[8][4] = {};
  bf16x8 a0[8], a1[8], b0[4], b1[4];

  // prologue: A(0), B(0) into buf0; B(1) into buf1  (12 loads)
  stageA(0, 0, ABUF(0));
  stageA(0, 1, ABUF(0));
  stageB(0, 0, ABUF(0));
  stageB(0, 1, ABUF(0));
  stageB(1, 0, ABUF(1));
  stageB(1, 1, ABUF(1));

  for (int t = 0; t < 64; ++t) {
    if (t == 63) {
      asm volatile("s_waitcnt vmcnt(0)" ::: "memory");
    } else {
      asm volatile("s_waitcnt vmcnt(4)" ::: "memory");
    }
    __builtin_amdgcn_s_barrier();
    char* Ab = ABUF(t & 1);

    // ---- ph0: b(ks0) + a(ks0) lo; stage A(t+1)h0 (other buffer)
#pragma unroll
    for (int nj = 0; nj < 4; ++nj)
      b0[nj] = *reinterpret_cast<const bf16x8*>(Ab + bBase0 + nj * 2048);
#pragma unroll
    for (int mi = 0; mi < 4; ++mi)
      a0[mi] = *reinterpret_cast<const bf16x8*>(Ab + aBase0 + mi * 2048);
    if (t < 63) stageA(t + 1, 0, ABUF((t + 1) & 1));
    LGKM0_FENCE
    __builtin_amdgcn_s_setprio(1);
#pragma unroll
    for (int mi = 0; mi < 4; ++mi)
#pragma unroll
      for (int nj = 0; nj < 4; ++nj)
        acc[mi][nj] = __builtin_amdgcn_mfma_f32_16x16x32_bf16(a0[mi], b0[nj],
                                                              acc[mi][nj], 0, 0, 0);
    __builtin_amdgcn_s_setprio(0);

    // ---- ph1: b(ks1) + a(ks0) hi; stage A(t+1)h1
#pragma unroll
    for (int nj = 0; nj < 4; ++nj)
      b1[nj] = *reinterpret_cast<const bf16x8*>(Ab + bBase1 + nj * 2048);
#pragma unroll
    for (int mi = 4; mi < 8; ++mi)
      a0[mi] = *reinterpret_cast<const bf16x8*>(Ab + aBase0 + mi * 2048);
    if (t < 63) stageA(t + 1, 1, ABUF((t + 1) & 1));
    LGKM0_FENCE
    __builtin_amdgcn_s_setprio(1);
#pragma unroll
    for (int mi = 4; mi < 8; ++mi)
#pragma unroll
      for (int nj = 0; nj < 4; ++nj)
        acc[mi][nj] = __builtin_amdgcn_mfma_f32_16x16x32_bf16(a0[mi], b0[nj],
                                                              acc[mi][nj], 0, 0, 0);
    __builtin_amdgcn_s_setprio(0);
    __builtin_amdgcn_sched_barrier(0);
    __builtin_amdgcn_s_barrier();  // mid: all B-reads of tile t retired block-wide

    // ---- ph2: a(ks1) lo; stage B(t+2)h0 (current buffer, B-region now free)
#pragma unroll
    for (int mi = 0; mi < 4; ++mi)
      a1[mi] = *reinterpret_cast<const bf16x8*>(Ab + aBase1 + mi * 2048);
    if (t < 62) stageB(t + 2, 0, Ab);
    LGKM0_FENCE
    __builtin_amdgcn_s_setprio(1);
#pragma unroll
    for (int mi = 0; mi < 4; ++mi)
#pragma unroll
      for (int nj = 0; nj < 4; ++nj)
        acc[mi][nj] = __builtin_amdgcn_mfma_f32_16x16x32_bf16(a1[mi], b1[nj],
                                                              acc[mi][nj], 0, 0, 0);
    __builtin_amdgcn_s_setprio(0);

    // ---- ph3: a(ks1) hi; stage B(t+2)h1
#pragma unroll
    for (int mi = 4; mi < 8; ++mi)
      a1[mi] = *reinterpret_cast<const bf16x8*>(Ab + aBase1 + mi * 2048);
    if (t < 62) stageB(t + 2, 1, Ab);
    LGKM0_FENCE
    __builtin_amdgcn_s_setprio(1);
#pragma unroll
    for (int mi = 4; mi < 8; ++mi)
#pragma unroll
      for (int nj = 0; nj < 4; ++nj)
        acc[mi][nj] = __builtin_amdgcn_mfma_f32_16x16x32_bf16(a1[mi], b1[nj],
                                                              acc[mi][nj], 0, 0, 0);
    __builtin_amdgcn_s_setprio(0);
    __builtin_amdgcn_sched_barrier(0);
  }

  // epilogue: C/D map col=lane&15, row=(lane>>4)*4+reg
  const int crow0 = bm0 + wm * 128 + (lane >> 4) * 4;
  const int ccol0 = bn0 + wn * 64 + r16;
#pragma unroll
  for (int nj = 0; nj < 4; ++nj) {
    float bv = bias[ccol0 + nj * 16];
#pragma unroll
    for (int mi = 0; mi < 8; ++mi)
#pragma unroll
      for (int r = 0; r < 4; ++r)
        out[(size_t)(crow0 + mi * 16 + r) * Ndim + ccol0 + nj * 16] =
            acc[mi][nj][r] + bv;
  }
#undef ABUF
}

// ---------------- fallback (ws too small): fp32 tiled GEMM, fold on stage ----------------
__global__ __launch_bounds__(256) void gemm_fallback(const float* __restrict__ x,
                                                     const float* __restrict__ W,
                                                     const float* __restrict__ bias,
                                                     const float* __restrict__ lA,
                                                     const float* __restrict__ lB,
                                                     float* __restrict__ out) {
  __shared__ float xs[16][64];
  __shared__ float wt[16][64];
  const int t = threadIdx.x;
  const int tx = t & 15, ty = t >> 4;
  const int bm0 = blockIdx.y * 64, bn0 = blockIdx.x * 64;
  float acc[4][4] = {};
  for (int kt = 0; kt < Kdim; kt += 16) {
    __syncthreads();
    for (int e = t; e < 1024; e += 256) {
      int m = e >> 4, k = e & 15;
      xs[k][m] = x[(size_t)(bm0 + m) * Kdim + kt + k];
    }
    for (int e = t; e < 1024; e += 256) {
      int n = e >> 4, k = e & 15;
      float v = W[(size_t)(bn0 + n) * Kdim + kt + k];
#pragma unroll
      for (int r = 0; r < 16; ++r)
        v += LORA_SCALE * lB[(bn0 + n) * 16 + r] * lA[r * Kdim + kt + k];
      wt[k][n] = v;
    }
    __syncthreads();
#pragma unroll
    for (int k = 0; k < 16; ++k) {
      float xa[4], wv[4];
#pragma unroll
      for (int i = 0; i < 4; ++i) xa[i] = xs[k][ty * 4 + i];
#pragma unroll
      for (int j = 0; j < 4; ++j) wv[j] = wt[k][tx * 4 + j];
#pragma unroll
      for (int i = 0; i < 4; ++i)
#pragma unroll
        for (int j = 0; j < 4; ++j) acc[i][j] += xa[i] * wv[j];
    }
  }
#pragma unroll
  for (int i = 0; i < 4; ++i)
#pragma unroll
    for (int j = 0; j < 4; ++j)
      out[(size_t)(bm0 + ty * 4 + i) * Ndim + bn0 + tx * 4 + j] =
          acc[i][j] + bias[bn0 + tx * 4 + j];
}

extern "C" void kernel_launch(void* const* d_in, const int* in_sizes, int n_in,
                              void* d_out, int out_size, void* d_ws, size_t ws_size,
                              hipStream_t stream) {
  const float* x = (const float*)d_in[0];
  const float* W = (const float*)d_in[1];
  const float* b = (const float*)d_in[2];
  const float* lA = (const float*)d_in[3];
  const float* lB = (const float*)d_in[4];
  float* out = (float*)d_out;

  const size_t xb_bytes = (size_t)Mdim * Kdim * sizeof(bf16);
  const size_t wb_bytes = (size_t)Ndim * Kdim * sizeof(bf16);

  if (ws_size >= xb_bytes + wb_bytes) {
    bf16* xb = (bf16*)d_ws;
    bf16* wb = (bf16*)((char*)d_ws + xb_bytes);
    cvt_x_kernel<<<4096, 256, 0, stream>>>(x, xb, Mdim * Kdim / 8);
    build_w_kernel<<<Ndim / 8, 256, 0, stream>>>(W, lA, lB, wb);
    (void)hipFuncSetAttribute((const void*)gemm8,
                              hipFuncAttributeMaxDynamicSharedMemorySize, 131072);
    gemm8<<<dim3((Mdim / 256) * (Ndim / 256)), dim3(512), 131072, stream>>>(xb, wb, b,
                                                                            out);
  } else {
    dim3 grid(Ndim / 64, Mdim / 64);
    gemm_fallback<<<grid, 64 * 4, 0, stream>>>(x, W, b, lA, lB, out);
  }
}